// Round 5
// baseline (226.634 us; speedup 1.0000x reference)
//
#include <hip/hip_runtime.h>

// y[i,j] = x[i,j] * w[j] + b[j], all fp32 (verified R3: passed, absmax 7.8e-3).
// x: (8192,4096), w/b: (4096,). Streaming 128 MiB R + 128 MiB W -> HBM-bound.
// R3 rocprof: harness re-poison fills (6.8 TB/s, 79 us each) dominate the
// 221 us timed window; kernel itself bounded < 78 us (absent from top-5).
// R4 fix: __builtin_nontemporal_* needs a clang native vector type, not
// HIP_vector_type float4 -> use ext_vector_type(4) float.

typedef __attribute__((ext_vector_type(4))) float f32x4;  // native vec, 16 B

#define IN_FEATURES 4096
#define VEC 4
#define WVECS (IN_FEATURES / VEC)      // 1024, power of 2
#define VPT 2                          // float4s per thread
#define BLOCK 256

__global__ __launch_bounds__(BLOCK) void one_to_one_kernel(
        const f32x4* __restrict__ x,
        const f32x4* __restrict__ w,
        const f32x4* __restrict__ b,
        f32x4* __restrict__ out,
        int nvec) {
    // Each block covers VPT contiguous 256-float4 chunks: lanes stay coalesced.
    int base = blockIdx.x * (BLOCK * VPT) + threadIdx.x;

#pragma unroll
    for (int t = 0; t < VPT; ++t) {
        int i = base + t * BLOCK;
        if (i >= nvec) return;
        int col = i & (WVECS - 1);

        f32x4 xv = __builtin_nontemporal_load(&x[i]);   // stream, don't cache
        f32x4 wv = w[col];   // 16 KiB w+b: keep cache-resident (no NT)
        f32x4 bv = b[col];
        f32x4 ov;
        ov.x = fmaf(xv.x, wv.x, bv.x);
        ov.y = fmaf(xv.y, wv.y, bv.y);
        ov.z = fmaf(xv.z, wv.z, bv.z);
        ov.w = fmaf(xv.w, wv.w, bv.w);
        __builtin_nontemporal_store(ov, &out[i]);       // stream, evict-first
    }
}

extern "C" void kernel_launch(void* const* d_in, const int* in_sizes, int n_in,
                              void* d_out, int out_size, void* d_ws, size_t ws_size,
                              hipStream_t stream) {
    const f32x4* x = (const f32x4*)d_in[0];  // dict order: x, weight, bias
    const f32x4* w = (const f32x4*)d_in[1];
    const f32x4* b = (const f32x4*)d_in[2];
    f32x4* out = (f32x4*)d_out;

    int nvec = out_size / VEC;                           // 8,388,608
    int grid = (nvec + BLOCK * VPT - 1) / (BLOCK * VPT); // 16384 blocks

    one_to_one_kernel<<<grid, BLOCK, 0, stream>>>(x, w, b, out, nvec);
}